// Round 3
// baseline (627.653 us; speedup 1.0000x reference)
//
#include <hip/hip_runtime.h>
#include <hip/hip_fp16.h>
#include <math.h>

#define EMB_DIM 256
#define NUM_EMB 2048
#define N_ROWS  65536            // 64*32*32
#define N_ELEM  16777216         // N_ROWS * EMB_DIM
#define EPS_GAP 5e-4f
#define DBIAS   48.0f            // distances biased into [32,64) binade

// ---- workspace layout (in 4-byte elements), total ~4.75 MB ----
#define IDX_OFF    0             // int[65536]
#define ESQ_OFF    65536         // float[2048]
#define EBIAS_OFF  67584         // float[2048]
#define HIST_OFF   69632        // int[2048]      -- memset region start
#define BKT_OFF    71680        // float[256]
#define CNT_OFF    71936        // int[64]        -- memset region end
#define FLG_OFF    72000        // int[65536]
#define CBT_OFF    137536       // float[2048][256]  (transposed codebook, fp32)
#define CBFH_OFF   661824       // f16 frag-order hi plane (1 MB)
#define CBFL_OFF   923968       // f16 frag-order lo plane (1 MB)

typedef __attribute__((ext_vector_type(8))) _Float16 half8;
typedef __attribute__((ext_vector_type(4))) float f32x4;
typedef unsigned int u32;

// ---------- ||e||^2 (R1/R2-proven summation) + biased half for packed argmin ----------
__global__ __launch_bounds__(256) void esq_k(const float* __restrict__ cb,
                                             float* __restrict__ esq,
                                             float* __restrict__ ebias) {
    int e = blockIdx.x * 256 + threadIdx.x;
    float s0 = 0.f, s1 = 0.f, s2 = 0.f, s3 = 0.f;
    for (int d = 0; d < EMB_DIM; d += 4) {
        float c0 = cb[(d + 0) * NUM_EMB + e];
        float c1 = cb[(d + 1) * NUM_EMB + e];
        float c2 = cb[(d + 2) * NUM_EMB + e];
        float c3 = cb[(d + 3) * NUM_EMB + e];
        s0 = fmaf(c0, c0, s0); s1 = fmaf(c1, c1, s1);
        s2 = fmaf(c2, c2, s2); s3 = fmaf(c3, c3, s3);
    }
    float s = (s0 + s1) + (s2 + s3);
    esq[e] = s;
    ebias[e] = DBIAS + 0.5f * s;
}

// ---------- transpose codebook: cbT fp32 + fragment-order f16 hi/lo planes ----------
// Frag layout: chunk (ct=col>>4, kt=k>>5, lane=lq*16+lm) holds cols ct*16+lm,
// k = kt*32+lq*8 .. +8, stored at f16 index ((ct*8+kt)*64 + lane)*8.
__global__ __launch_bounds__(256) void prep_cbt(const float* __restrict__ cb,
                                                float* __restrict__ cbT,
                                                __half* __restrict__ cbFh,
                                                __half* __restrict__ cbFl) {
    __shared__ float lt[64][65];
    int t = threadIdx.x;
    int et = (blockIdx.x & 31) * 64;   // e-tile base
    int dt = (blockIdx.x >> 5) * 64;   // d-tile base
    #pragma unroll
    for (int p = 0; p < 4; ++p) {
        int d  = p * 16 + (t >> 4);
        int e4 = (t & 15) * 4;
        const float4 v = *(const float4*)&cb[(dt + d) * NUM_EMB + et + e4];
        lt[d][e4] = v.x; lt[d][e4 + 1] = v.y; lt[d][e4 + 2] = v.z; lt[d][e4 + 3] = v.w;
    }
    __syncthreads();
    // fp32 transposed (for fallback + quant)
    #pragma unroll
    for (int p = 0; p < 4; ++p) {
        int e  = p * 16 + (t >> 4);
        int d4 = (t & 15) * 4;
        float4 v = make_float4(lt[d4][e], lt[d4 + 1][e], lt[d4 + 2][e], lt[d4 + 3][e]);
        *(float4*)&cbT[(size_t)(et + e) * EMB_DIM + dt + d4] = v;
    }
    // fragment-order f16 hi/lo: 512 chunks per tile, 2 per thread
    #pragma unroll
    for (int q = 0; q < 2; ++q) {
        int cl = t * 2 + q;
        int col_l = cl >> 3, kc = cl & 7;
        int col = et + col_l;
        int kglob = dt + kc * 8;
        _Float16 hi[8], lo[8];
        #pragma unroll
        for (int j = 0; j < 8; ++j) {
            float v = lt[kc * 8 + j][col_l];
            __half h = __float2half(v);
            hi[j] = *(_Float16*)&h;
            __half l = __float2half(v - __half2float(h));
            lo[j] = *(_Float16*)&l;
        }
        int ct = col >> 4, lm = col & 15;
        int kt = kglob >> 5, lq = (kglob >> 3) & 3;
        size_t dst = ((size_t)(ct * 8 + kt) * 64 + lq * 16 + lm) * 8;
        *(half8*)&cbFh[dst] = *(half8*)hi;
        *(half8*)&cbFl[dst] = *(half8*)lo;
    }
}

// ---------- x -> fp16 hi/lo planes (plain [row][k] layout, in d_out scratch) ----------
__global__ __launch_bounds__(256) void prep_x(const float* __restrict__ x,
                                              __half* __restrict__ xh,
                                              __half* __restrict__ xl) {
    int t = threadIdx.x;
    int row = blockIdx.x * 4 + (t >> 6);
    int c = (t & 63) * 4;
    const float4 v = *(const float4*)&x[(size_t)row * EMB_DIM + c];
    float a[4] = {v.x, v.y, v.z, v.w};
    unsigned short hb[4], lb[4];
    #pragma unroll
    for (int i = 0; i < 4; ++i) {
        __half h = __float2half(a[i]);
        __half l = __float2half(a[i] - __half2float(h));
        hb[i] = __half_as_ushort(h); lb[i] = __half_as_ushort(l);
    }
    *(ushort4*)&xh[(size_t)row * EMB_DIM + c] = make_ushort4(hb[0], hb[1], hb[2], hb[3]);
    *(ushort4*)&xl[(size_t)row * EMB_DIM + c] = make_ushort4(lb[0], lb[1], lb[2], lb[3]);
}

// ---------- main: barrier-free MFMA distance argmin ----------
// 1024 blocks x 256 thr. Block = 64 rows. A (x, hi+lo) staged ONCE to LDS in
// frag order; B-frags streamed global->VGPR from frag-order codebook (L2-hot).
// Packed-float argmin: d~ = (DBIAS + esq/2) - sim, 5 low mantissa bits = (nt,g) id.
__global__ __launch_bounds__(256, 2) void argmin_mfma2(
    const __half* __restrict__ xh_, const __half* __restrict__ xl_,
    const __half* __restrict__ cbFh_, const __half* __restrict__ cbFl_,
    const float* __restrict__ ebias,
    int* __restrict__ idx_out, int* __restrict__ cnt, int* __restrict__ flg) {

    __shared__ char smem[65536];                  // 64 KB: A frags; reused for reduce
    _Float16* sa_h = (_Float16*)smem;             // chunks p=kt*4+f: p*512 + L*8
    _Float16* sa_l = sa_h + 16384;

    const _Float16* xh  = (const _Float16*)xh_;
    const _Float16* cbFh = (const _Float16*)cbFh_;
    const _Float16* cbFl = (const _Float16*)cbFl_;

    const int t = threadIdx.x;
    const int w = t >> 6, L = t & 63;
    const int lm = L & 15, lq = L >> 4;
    const int rowbase = blockIdx.x * 64;

    // ---- stage A once: 8 chunks per thread per plane ----
    {
        const _Float16* xl = (const _Float16*)xl_;
        #pragma unroll
        for (int i = 0; i < 8; ++i) {
            int c = t + i * 256;                  // chunk id = p*64 + lane
            int cl = c & 63, p = c >> 6;
            int f = p & 3, kt = p >> 2;
            size_t src = (size_t)(rowbase + f * 16 + (cl & 15)) * EMB_DIM
                       + kt * 32 + (cl >> 4) * 8;
            *(half8*)&sa_h[c * 8] = *(const half8*)&xh[src];
            *(half8*)&sa_l[c * 8] = *(const half8*)&xl[src];
        }
    }
    __syncthreads();                              // the ONLY barrier before reduce

    float m1[16], m2[16];
    #pragma unroll
    for (int s = 0; s < 16; ++s) { m1[s] = 3.4e38f; m2[s] = 3.4e38f; }

    const int L8 = L * 8;
    const char* bbase_h = (const char*)cbFh + (size_t)(w * 16) * 1024 + L * 16;
    const char* bbase_l = (const char*)cbFl + (size_t)(w * 16) * 1024 + L * 16;
    const u32 mask = 0xFFFFFFE0u;

    for (int nt = 0; nt < 16; ++nt) {
        // ebias for this tile's two 16-col groups (prefetch; L2-hot)
        float eb0 = ebias[nt * 128 + w * 32 + lm];
        float eb1 = ebias[nt * 128 + w * 32 + 16 + lm];

        f32x4 acc[4][2];
        #pragma unroll
        for (int f = 0; f < 4; ++f) { acc[f][0] = (f32x4){0,0,0,0}; acc[f][1] = (f32x4){0,0,0,0}; }

        const char* bh_nt = bbase_h + (size_t)nt * 64 * 1024;
        const char* bl_nt = bbase_l + (size_t)nt * 64 * 1024;

        half8 bc[4];   // [g*2+plane]: g0h, g0l, g1h, g1l
        bc[0] = *(const half8*)(bh_nt);
        bc[1] = *(const half8*)(bl_nt);
        bc[2] = *(const half8*)(bh_nt + 8 * 1024);
        bc[3] = *(const half8*)(bl_nt + 8 * 1024);

        #pragma unroll
        for (int kt = 0; kt < 8; ++kt) {
            half8 bn[4];
            if (kt < 7) {
                bn[0] = *(const half8*)(bh_nt + (kt + 1) * 1024);
                bn[1] = *(const half8*)(bl_nt + (kt + 1) * 1024);
                bn[2] = *(const half8*)(bh_nt + (8 + kt + 1) * 1024);
                bn[3] = *(const half8*)(bl_nt + (8 + kt + 1) * 1024);
            }
            half8 ah[4], al[4];
            #pragma unroll
            for (int f = 0; f < 4; ++f) {
                ah[f] = *(const half8*)&sa_h[(kt * 4 + f) * 512 + L8];
                al[f] = *(const half8*)&sa_l[(kt * 4 + f) * 512 + L8];
            }
            #pragma unroll
            for (int f = 0; f < 4; ++f)
                #pragma unroll
                for (int g = 0; g < 2; ++g) {
                    acc[f][g] = __builtin_amdgcn_mfma_f32_16x16x32_f16(ah[f], bc[g*2],   acc[f][g], 0, 0, 0);
                    acc[f][g] = __builtin_amdgcn_mfma_f32_16x16x32_f16(ah[f], bc[g*2+1], acc[f][g], 0, 0, 0);
                    acc[f][g] = __builtin_amdgcn_mfma_f32_16x16x32_f16(al[f], bc[g*2],   acc[f][g], 0, 0, 0);
                }
            if (kt < 7) { bc[0]=bn[0]; bc[1]=bn[1]; bc[2]=bn[2]; bc[3]=bn[3]; }
        }

        // packed epilogue: 5 VALU / element
        #pragma unroll
        for (int g = 0; g < 2; ++g) {
            float eb = g ? eb1 : eb0;
            u32 id = (u32)(nt * 2 + g);           // wave-uniform
            #pragma unroll
            for (int f = 0; f < 4; ++f)
                #pragma unroll
                for (int r = 0; r < 4; ++r) {
                    float d = eb - acc[f][g][r];
                    float dq = __uint_as_float((__float_as_uint(d) & mask) | id);
                    int s = f * 4 + r;
                    float hi = fmaxf(m1[s], dq);
                    m1[s] = fminf(m1[s], dq);
                    m2[s] = fminf(m2[s], hi);
                }
        }
    }

    // ---- block reduce: 64 candidates per row (reuse smem) ----
    __syncthreads();
    float* rd = (float*)smem;                     // [64][64]
    int*   ri = (int*)smem + 4096;
    float* r2 = (float*)smem + 8192;
    #pragma unroll
    for (int f = 0; f < 4; ++f)
        #pragma unroll
        for (int r = 0; r < 4; ++r) {
            int s = f * 4 + r;
            int row = f * 16 + lq * 4 + r;
            int c = w * 16 + lm;
            u32 b = __float_as_uint(m1[s]);
            u32 id = b & 31u;
            rd[row * 64 + c] = __uint_as_float(b & mask);
            ri[row * 64 + c] = (int)(id >> 1) * 128 + w * 32 + (int)(id & 1) * 16 + lm;
            r2[row * 64 + c] = __uint_as_float(__float_as_uint(m2[s]) & mask);
        }
    __syncthreads();
    if (t < 64) {
        int row = t;
        float g1 = rd[row * 64]; int gi = ri[row * 64]; float g2 = r2[row * 64];
        for (int c = 1; c < 64; ++c) {
            float d = rd[row * 64 + c]; int ic = ri[row * 64 + c]; float dc2 = r2[row * 64 + c];
            if (d < g1 || (d == g1 && ic < gi)) {
                g2 = fminf(fminf(g2, dc2), g1); g1 = d; gi = ic;
            } else {
                g2 = fminf(g2, d);
            }
        }
        idx_out[rowbase + row] = gi;
        if (g2 - g1 < EPS_GAP) {
            int p = atomicAdd(cnt, 1);
            flg[p] = rowbase + row;
        }
    }
}

// ---------- exact fp32 re-check for flagged rows (R2-proven formula) ----------
__global__ __launch_bounds__(256) void fallback_k(const float* __restrict__ x,
                                                  const float* __restrict__ cbT,
                                                  const float* __restrict__ esq,
                                                  const int* __restrict__ cnt,
                                                  const int* __restrict__ rows,
                                                  int* __restrict__ idx) {
    __shared__ float xr[256];
    __shared__ float sd[256];
    __shared__ int   si[256];
    __shared__ float sq[256];
    int t = threadIdx.x;
    int n = *cnt;
    for (int fi = blockIdx.x; fi < n; fi += gridDim.x) {
        int row = rows[fi];
        __syncthreads();
        float v = x[(size_t)row * EMB_DIM + t];
        xr[t] = v;
        sq[t] = v * v;
        __syncthreads();
        // xsq via tree reduce (row-constant: exact order irrelevant to argmin)
        for (int stp = 128; stp > 0; stp >>= 1) {
            if (t < stp) sq[t] += sq[t + stp];
            __syncthreads();
        }
        float xq = sq[0];
        float bd = 3.4e38f; int bi = 0x7fffffff;
        for (int e = t; e < NUM_EMB; e += 256) {
            const float* cr = &cbT[(size_t)e * EMB_DIM];
            float s0 = 0.f, s1 = 0.f, s2 = 0.f, s3 = 0.f;
            for (int d = 0; d < EMB_DIM; d += 4) {
                const float4 c4 = *(const float4*)&cr[d];
                s0 = fmaf(xr[d], c4.x, s0);
                s1 = fmaf(xr[d + 1], c4.y, s1);
                s2 = fmaf(xr[d + 2], c4.z, s2);
                s3 = fmaf(xr[d + 3], c4.w, s3);
            }
            float sim = (s0 + s1) + (s2 + s3);
            float dd = (xq + esq[e]) - 2.0f * sim;
            if (dd < bd) { bd = dd; bi = e; }     // e ascends per thread
        }
        sd[t] = bd; si[t] = bi;
        __syncthreads();
        for (int stp = 128; stp > 0; stp >>= 1) {
            if (t < stp) {
                if (sd[t + stp] < sd[t] || (sd[t + stp] == sd[t] && si[t + stp] < si[t])) {
                    sd[t] = sd[t + stp]; si[t] = si[t + stp];
                }
            }
            __syncthreads();
        }
        if (t == 0) idx[row] = si[0];
    }
}

// ---------- quantize + straight-through + loss partials + histogram ----------
// 4096 blocks x 256 thr; 16 rows/block; 16 fp32 per thread (4x float4).
__global__ __launch_bounds__(256) void quant_k(const float* __restrict__ x,
                                               const float* __restrict__ cbT,
                                               const int* __restrict__ idx,
                                               float* __restrict__ out,
                                               float* __restrict__ bkt,
                                               int* __restrict__ hist) {
    __shared__ float red[256];
    int t = threadIdx.x;
    int row = blockIdx.x * 16 + (t >> 4);
    int c0 = (t & 15) * 16;
    int e = idx[row];
    const float4* xp = (const float4*)&x[(size_t)row * EMB_DIM + c0];
    const float4* qp = (const float4*)&cbT[(size_t)e * EMB_DIM + c0];
    float4* op = (float4*)&out[(size_t)row * EMB_DIM + c0];
    float s = 0.f;
    #pragma unroll
    for (int j = 0; j < 4; ++j) {
        float4 xv = xp[j], qv = qp[j];
        float4 ov;
        ov.x = xv.x + (qv.x - xv.x); ov.y = xv.y + (qv.y - xv.y);
        ov.z = xv.z + (qv.z - xv.z); ov.w = xv.w + (qv.w - xv.w);
        op[j] = ov;
        float dx = xv.x - qv.x, dy = xv.y - qv.y, dz = xv.z - qv.z, dw = xv.w - qv.w;
        s += dx * dx + dy * dy + dz * dz + dw * dw;
    }
    red[t] = s;
    __syncthreads();
    for (int stp = 128; stp > 0; stp >>= 1) {
        if (t < stp) red[t] += red[t + stp];
        __syncthreads();
    }
    if (t == 0) atomicAdd(&bkt[blockIdx.x & 255], red[0]);
    if ((t & 15) == 0) atomicAdd(&hist[e], 1);
}

// ---------- finalize loss + perplexity ----------
__global__ __launch_bounds__(256) void final_k(const float* __restrict__ bkt,
                                               const int* __restrict__ hist,
                                               float* __restrict__ out) {
    int t = threadIdx.x;
    double ls = (double)bkt[t];
    double ps = 0.0;
    for (int i = t; i < NUM_EMB; i += 256) {
        double p = (double)hist[i] / (double)N_ROWS;
        ps += p * log(p + 1e-10);
    }
    __shared__ double sdd[256], spp[256];
    sdd[t] = ls; spp[t] = ps;
    __syncthreads();
    for (int s = 128; s > 0; s >>= 1) {
        if (t < s) { sdd[t] += sdd[t + s]; spp[t] += spp[t + s]; }
        __syncthreads();
    }
    if (t == 0) {
        out[N_ELEM + 0] = (float)(1.25 * sdd[0] / (double)N_ELEM);
        out[N_ELEM + 1] = (float)exp(-spp[0]);
    }
}

extern "C" void kernel_launch(void* const* d_in, const int* in_sizes, int n_in,
                              void* d_out, int out_size, void* d_ws, size_t ws_size,
                              hipStream_t stream) {
    const float* x  = (const float*)d_in[0];
    const float* cb = (const float*)d_in[1];
    float* out = (float*)d_out;

    float* ws_f = (float*)d_ws;
    int*   ws_i = (int*)d_ws;
    int*   idx   = ws_i + IDX_OFF;
    float* esq   = ws_f + ESQ_OFF;
    float* ebias = ws_f + EBIAS_OFF;
    int*   hist  = ws_i + HIST_OFF;
    float* bkt   = ws_f + BKT_OFF;
    int*   cnt   = ws_i + CNT_OFF;
    int*   flg   = ws_i + FLG_OFF;
    float* cbT   = ws_f + CBT_OFF;
    __half* cbFh = (__half*)(ws_f + CBFH_OFF);
    __half* cbFl = (__half*)(ws_f + CBFL_OFF);

    // x hi/lo fp16 planes live in d_out (overwritten by quant_k at the end)
    __half* xh = (__half*)d_out;
    __half* xl = (__half*)((char*)d_out + (size_t)N_ELEM * 2);

    // zero hist + bkt + cnt (contiguous)
    hipMemsetAsync((char*)d_ws + (size_t)HIST_OFF * 4, 0,
                   (size_t)(CNT_OFF + 64 - HIST_OFF) * 4, stream);

    esq_k<<<NUM_EMB / 256, 256, 0, stream>>>(cb, esq, ebias);
    prep_cbt<<<128, 256, 0, stream>>>(cb, cbT, cbFh, cbFl);
    prep_x<<<N_ROWS / 4, 256, 0, stream>>>(x, xh, xl);
    argmin_mfma2<<<N_ROWS / 64, 256, 0, stream>>>(xh, xl, cbFh, cbFl, ebias, idx, cnt, flg);
    fallback_k<<<1024, 256, 0, stream>>>(x, cbT, esq, cnt, flg, idx);
    quant_k<<<N_ROWS / 16, 256, 0, stream>>>(x, cbT, idx, out, bkt, hist);
    final_k<<<1, 256, 0, stream>>>(bkt, hist, out);
}